// Round 14
// baseline (232.262 us; speedup 1.0000x reference)
//
#include <hip/hip_runtime.h>

#define NN 50000
#define D 128
#define EPS 1e-8f
#define NSCAN 50176          // 49 * 1024 >= NN
#define NB_SCAN 49

__device__ __forceinline__ unsigned short f2b(float f) {
    unsigned int u = __float_as_uint(f);
    u += 0x7FFFu + ((u >> 16) & 1u);      // round-to-nearest-even
    return (unsigned short)(u >> 16);
}
__device__ __forceinline__ float b2f(unsigned short s) {
    return __uint_as_float(((unsigned int)s) << 16);
}

__device__ __forceinline__ void edge_fma4(float4& a, ushort4 r, float w) {
    a.x = fmaf(b2f(r.x), w, a.x);
    a.y = fmaf(b2f(r.y), w, a.y);
    a.z = fmaf(b2f(r.z), w, a.z);
    a.w = fmaf(b2f(r.w), w, a.w);
}

// ---------------- prep: dst histogram + x->bf16 + WT build (fused) ----------------
__global__ __launch_bounds__(256) void prep_kernel(
        const int* __restrict__ dst, int* __restrict__ count,
        const float* __restrict__ x, ushort* __restrict__ xb,
        const float* __restrict__ Ws, const float* __restrict__ Wn,
        float* __restrict__ WT, int E) {
    int i = blockIdx.x * 256 + threadIdx.x;
    if (i < E) atomicAdd(&count[dst[i]], 1);
    if (i < NN * D / 4) {
        float4 v = ((const float4*)x)[i];
        ushort4 o;
        o.x = f2b(v.x); o.y = f2b(v.y); o.z = f2b(v.z); o.w = f2b(v.w);
        ((ushort4*)xb)[i] = o;
    }
    if (i < 256 * 128) {
        int k = i >> 7;
        int j = i & 127;
        float v = (k < 128) ? Ws[j * 128 + k] : Wn[j * 128 + (k - 128)];
        WT[i] = v;
    }
}

// ---------------- scan step 1: pad counts to even, per-block exclusive scan ----------------
__global__ __launch_bounds__(1024) void scan1_kernel(const int* __restrict__ count,
                                                     int* __restrict__ offsets,
                                                     int* __restrict__ bsum) {
    __shared__ int tmp[1024];
    int t = threadIdx.x;
    int gid = blockIdx.x * 1024 + t;
    int c = (count[gid] + 1) & ~1;        // pad each node to even edge count
    tmp[t] = c;
    __syncthreads();
    for (int off = 1; off < 1024; off <<= 1) {
        int v = (t >= off) ? tmp[t - off] : 0;
        __syncthreads();
        tmp[t] += v;
        __syncthreads();
    }
    offsets[gid] = tmp[t] - c;
    if (t == 1023) bsum[blockIdx.x] = tmp[t];
}

// ---------------- scan step 2+3: block-sum scan + add + cursor + explicit pad writes ----------------
__global__ __launch_bounds__(1024) void scan23_kernel(int* __restrict__ offsets,
                                                      const int* __restrict__ bsum,
                                                      int* __restrict__ cursor,
                                                      const int* __restrict__ count,
                                                      int2* __restrict__ edge_sw) {
    __shared__ int bs[64];
    int t = threadIdx.x;
    if (t < 64) {
        int orig = (t < NB_SCAN) ? bsum[t] : 0;
        int v = orig;
        #pragma unroll
        for (int off = 1; off < 64; off <<= 1) {
            int u = __shfl_up(v, off);
            if (t >= off) v += u;
        }
        bs[t] = v - orig;    // exclusive
    }
    __syncthreads();
    int gid = blockIdx.x * 1024 + t;
    int val = offsets[gid] + bs[blockIdx.x];
    offsets[gid] = val;
    cursor[gid] = val;
    int cnt = count[gid];
    if (cnt & 1) {
        // odd count -> one pad slot at the end of this node's segment; must read as {0, 0.0f}
        edge_sw[val + cnt] = make_int2(0, 0);
    }
}

// ---------------- permute edges into CSR order (memory-side 8B atomic stores) ----------------
__global__ __launch_bounds__(256) void csr_scatter_kernel(
        const int* __restrict__ src, const int* __restrict__ dst,
        const float* __restrict__ ew, int* __restrict__ cursor,
        unsigned long long* __restrict__ edge_sw, int E) {
    int e = blockIdx.x * 256 + threadIdx.x;
    if (e >= E) return;
    int d = dst[e];
    int pos = atomicAdd(&cursor[d], 1);
    unsigned long long val = ((unsigned long long)(unsigned)__float_as_int(ew[e]) << 32)
                           | (unsigned)src[e];
    atomicExch(&edge_sw[pos], val);   // memory-side 8B write, no L2 write-allocate RMW
}

// ---------------- fused gather(bf16, 16-edge chunks) + dual GEMM + bias (R13 verbatim) ----------------
__global__ __launch_bounds__(256) void fused_out_kernel(
        const float* __restrict__ x, const ushort* __restrict__ xb,
        const int* __restrict__ offsets, const int2* __restrict__ edge_sw,
        const float* __restrict__ WT, const float* __restrict__ b_self,
        const float* __restrict__ bias, float* __restrict__ out) {
    __shared__ float HN[32][128];
    int tid = threadIdx.x;
    int v0 = blockIdx.x * 32;
    int lane = tid & 63;
    int wid = tid >> 6;
    int half = lane >> 5;
    int l32 = lane & 31;

    for (int q = 0; q < 8; ++q) {
        int nn = wid * 8 + q;
        int v = v0 + nn;
        float4 acc = make_float4(0.f, 0.f, 0.f, 0.f);
        float wsum = 0.f;
        if (v < NN) {
            int beg = offsets[v];
            int end = offsets[v + 1];
            int cnt = end - beg;               // even
            int i = beg;
            int n16 = cnt & ~15;
            for (; i < beg + n16; i += 16) {
                const int2* ebase = edge_sw + i + 8 * half;
                int4 mA = *(const int4*)(ebase + 0);
                int4 mB = *(const int4*)(ebase + 2);
                int4 mC = *(const int4*)(ebase + 4);
                int4 mD = *(const int4*)(ebase + 6);
                float w0 = __int_as_float(mA.y), w1 = __int_as_float(mA.w);
                float w2 = __int_as_float(mB.y), w3 = __int_as_float(mB.w);
                float w4 = __int_as_float(mC.y), w5 = __int_as_float(mC.w);
                float w6 = __int_as_float(mD.y), w7 = __int_as_float(mD.w);
                ushort4 r0 = *((const ushort4*)(xb + (size_t)mA.x * D) + l32);
                ushort4 r1 = *((const ushort4*)(xb + (size_t)mA.z * D) + l32);
                ushort4 r2 = *((const ushort4*)(xb + (size_t)mB.x * D) + l32);
                ushort4 r3 = *((const ushort4*)(xb + (size_t)mB.z * D) + l32);
                ushort4 r4 = *((const ushort4*)(xb + (size_t)mC.x * D) + l32);
                ushort4 r5 = *((const ushort4*)(xb + (size_t)mC.z * D) + l32);
                ushort4 r6 = *((const ushort4*)(xb + (size_t)mD.x * D) + l32);
                ushort4 r7 = *((const ushort4*)(xb + (size_t)mD.z * D) + l32);
                edge_fma4(acc, r0, w0); edge_fma4(acc, r1, w1);
                edge_fma4(acc, r2, w2); edge_fma4(acc, r3, w3);
                edge_fma4(acc, r4, w4); edge_fma4(acc, r5, w5);
                edge_fma4(acc, r6, w6); edge_fma4(acc, r7, w7);
                wsum += ((w0 + w1) + (w2 + w3)) + ((w4 + w5) + (w6 + w7));
            }
            if (cnt & 8) {
                const int2* ebase = edge_sw + i + 4 * half;
                int4 mA = *(const int4*)(ebase + 0);
                int4 mB = *(const int4*)(ebase + 2);
                float w0 = __int_as_float(mA.y), w1 = __int_as_float(mA.w);
                float w2 = __int_as_float(mB.y), w3 = __int_as_float(mB.w);
                ushort4 r0 = *((const ushort4*)(xb + (size_t)mA.x * D) + l32);
                ushort4 r1 = *((const ushort4*)(xb + (size_t)mA.z * D) + l32);
                ushort4 r2 = *((const ushort4*)(xb + (size_t)mB.x * D) + l32);
                ushort4 r3 = *((const ushort4*)(xb + (size_t)mB.z * D) + l32);
                edge_fma4(acc, r0, w0); edge_fma4(acc, r1, w1);
                edge_fma4(acc, r2, w2); edge_fma4(acc, r3, w3);
                wsum += (w0 + w1) + (w2 + w3);
                i += 8;
            }
            if (cnt & 4) {
                int4 mA = *(const int4*)(edge_sw + i + 2 * half);
                float w0 = __int_as_float(mA.y), w1 = __int_as_float(mA.w);
                ushort4 r0 = *((const ushort4*)(xb + (size_t)mA.x * D) + l32);
                ushort4 r1 = *((const ushort4*)(xb + (size_t)mA.z * D) + l32);
                edge_fma4(acc, r0, w0); edge_fma4(acc, r1, w1);
                wsum += w0 + w1;
                i += 4;
            }
            if ((cnt & 2) && half == 0) {
                int4 mA = *(const int4*)(edge_sw + i);
                float w0 = __int_as_float(mA.y), w1 = __int_as_float(mA.w);
                ushort4 r0 = *((const ushort4*)(xb + (size_t)mA.x * D) + l32);
                ushort4 r1 = *((const ushort4*)(xb + (size_t)mA.z * D) + l32);
                edge_fma4(acc, r0, w0); edge_fma4(acc, r1, w1);
                wsum += w0 + w1;
            }
        }
        acc.x += __shfl_xor(acc.x, 32);
        acc.y += __shfl_xor(acc.y, 32);
        acc.z += __shfl_xor(acc.z, 32);
        acc.w += __shfl_xor(acc.w, 32);
        wsum  += __shfl_xor(wsum, 32);
        if (half == 0) {
            float inv = 1.0f / (wsum + EPS);
            *(float4*)&HN[nn][l32 * 4] =
                make_float4(acc.x * inv, acc.y * inv, acc.z * inv, acc.w * inv);
        }
    }
    __syncthreads();

    int j0 = (tid & 31) * 4;
    int ns = tid >> 5;
    float acc[4][4];
    #pragma unroll
    for (int n = 0; n < 4; ++n)
        #pragma unroll
        for (int j = 0; j < 4; ++j) acc[n][j] = 0.f;

    int rowc[4];
    #pragma unroll
    for (int n = 0; n < 4; ++n) {
        int rv = v0 + ns * 4 + n;
        rowc[n] = (rv < NN) ? rv : (NN - 1);
    }

    for (int k4 = 0; k4 < 128; k4 += 4) {
        float4 w0 = *(const float4*)(WT + (k4 + 0) * D + j0);
        float4 w1 = *(const float4*)(WT + (k4 + 1) * D + j0);
        float4 w2 = *(const float4*)(WT + (k4 + 2) * D + j0);
        float4 w3 = *(const float4*)(WT + (k4 + 3) * D + j0);
        #pragma unroll
        for (int n = 0; n < 4; ++n) {
            float4 a = *(const float4*)(x + (size_t)rowc[n] * D + k4);
            acc[n][0] = fmaf(a.x, w0.x, fmaf(a.y, w1.x, fmaf(a.z, w2.x, fmaf(a.w, w3.x, acc[n][0]))));
            acc[n][1] = fmaf(a.x, w0.y, fmaf(a.y, w1.y, fmaf(a.z, w2.y, fmaf(a.w, w3.y, acc[n][1]))));
            acc[n][2] = fmaf(a.x, w0.z, fmaf(a.y, w1.z, fmaf(a.z, w2.z, fmaf(a.w, w3.z, acc[n][2]))));
            acc[n][3] = fmaf(a.x, w0.w, fmaf(a.y, w1.w, fmaf(a.z, w2.w, fmaf(a.w, w3.w, acc[n][3]))));
        }
    }
    for (int k4 = 0; k4 < 128; k4 += 4) {
        float4 w0 = *(const float4*)(WT + (128 + k4 + 0) * D + j0);
        float4 w1 = *(const float4*)(WT + (128 + k4 + 1) * D + j0);
        float4 w2 = *(const float4*)(WT + (128 + k4 + 2) * D + j0);
        float4 w3 = *(const float4*)(WT + (128 + k4 + 3) * D + j0);
        #pragma unroll
        for (int n = 0; n < 4; ++n) {
            float4 a = *(const float4*)&HN[ns * 4 + n][k4];
            acc[n][0] = fmaf(a.x, w0.x, fmaf(a.y, w1.x, fmaf(a.z, w2.x, fmaf(a.w, w3.x, acc[n][0]))));
            acc[n][1] = fmaf(a.x, w0.y, fmaf(a.y, w1.y, fmaf(a.z, w2.y, fmaf(a.w, w3.y, acc[n][1]))));
            acc[n][2] = fmaf(a.x, w0.z, fmaf(a.y, w1.z, fmaf(a.z, w2.z, fmaf(a.w, w3.z, acc[n][2]))));
            acc[n][3] = fmaf(a.x, w0.w, fmaf(a.y, w1.w, fmaf(a.z, w2.w, fmaf(a.w, w3.w, acc[n][3]))));
        }
    }

    float4 b  = *(const float4*)(b_self + j0);
    float4 bp = *(const float4*)(bias + j0);
    b.x += bp.x; b.y += bp.y; b.z += bp.z; b.w += bp.w;

    #pragma unroll
    for (int n = 0; n < 4; ++n) {
        int v = v0 + ns * 4 + n;
        if (v < NN) {
            float4 o;
            o.x = acc[n][0] + b.x;
            o.y = acc[n][1] + b.y;
            o.z = acc[n][2] + b.z;
            o.w = acc[n][3] + b.w;
            *(float4*)(out + (size_t)v * D + j0) = o;
        }
    }
}

extern "C" void kernel_launch(void* const* d_in, const int* in_sizes, int n_in,
                              void* d_out, int out_size, void* d_ws, size_t ws_size,
                              hipStream_t stream) {
    const float* x   = (const float*)d_in[0];
    const int*   src = (const int*)d_in[1];
    const int*   dst = (const int*)d_in[2];
    const float* ew  = (const float*)d_in[3];
    const float* Ws  = (const float*)d_in[4];
    const float* bs  = (const float*)d_in[5];
    const float* Wn  = (const float*)d_in[6];
    const float* bp  = (const float*)d_in[7];
    float* out = (float*)d_out;

    int E = in_sizes[1];
    int EPAD = E + NSCAN;                       // room for 1 pad edge per node

    // workspace layout (4B units)
    int*  wsi     = (int*)d_ws;
    int*  count   = wsi;                        // NSCAN
    int2* edge_sw = (int2*)(wsi + NSCAN);       // EPAD int2 (16B-aligned)
    int*  offsets = wsi + NSCAN + 2 * EPAD;     // NSCAN
    int*  cursor  = offsets + NSCAN;            // NSCAN
    int*  bsum    = cursor + NSCAN;             // 64
    float* WT     = (float*)(bsum + 64);        // 256*128 floats
    ushort* xb    = (ushort*)(WT + 256 * 128);  // NN*D bf16

    // zero only count (200 KB); pad slots written explicitly in scan23
    hipMemsetAsync(count, 0, (size_t)NSCAN * sizeof(int), stream);

    int ncvt = NN * D / 4;
    int nmax = (E > ncvt) ? E : ncvt;
    prep_kernel<<<(nmax + 255) / 256, 256, 0, stream>>>(dst, count, x, xb, Ws, Wn, WT, E);

    scan1_kernel<<<NB_SCAN, 1024, 0, stream>>>(count, offsets, bsum);
    scan23_kernel<<<NB_SCAN, 1024, 0, stream>>>(offsets, bsum, cursor, count, edge_sw);
    csr_scatter_kernel<<<(E + 255) / 256, 256, 0, stream>>>(src, dst, ew, cursor,
                                                            (unsigned long long*)edge_sw, E);

    fused_out_kernel<<<(NN + 31) / 32, 256, 0, stream>>>(x, xb, offsets, edge_sw,
                                                         WT, bs, bp, out);
}

// Round 15
// 218.298 us; speedup vs baseline: 1.0640x; 1.0640x over previous
//
#include <hip/hip_runtime.h>

#define NN 50000
#define D 128
#define EPS 1e-8f
#define NSCAN 50176          // 49 * 1024 >= NN
#define NB_SCAN 49

__device__ __forceinline__ unsigned short f2b(float f) {
    unsigned int u = __float_as_uint(f);
    u += 0x7FFFu + ((u >> 16) & 1u);      // round-to-nearest-even
    return (unsigned short)(u >> 16);
}
__device__ __forceinline__ float b2f(unsigned short s) {
    return __uint_as_float(((unsigned int)s) << 16);
}

__device__ __forceinline__ void edge_fma4(float4& a, ushort4 r, float w) {
    a.x = fmaf(b2f(r.x), w, a.x);
    a.y = fmaf(b2f(r.y), w, a.y);
    a.z = fmaf(b2f(r.z), w, a.z);
    a.w = fmaf(b2f(r.w), w, a.w);
}

// ---------------- prep: dst histogram + x->bf16 + WT build (fused) ----------------
__global__ __launch_bounds__(256) void prep_kernel(
        const int* __restrict__ dst, int* __restrict__ count,
        const float* __restrict__ x, ushort* __restrict__ xb,
        const float* __restrict__ Ws, const float* __restrict__ Wn,
        float* __restrict__ WT, int E) {
    int i = blockIdx.x * 256 + threadIdx.x;
    if (i < E) atomicAdd(&count[dst[i]], 1);
    if (i < NN * D / 4) {
        float4 v = ((const float4*)x)[i];
        ushort4 o;
        o.x = f2b(v.x); o.y = f2b(v.y); o.z = f2b(v.z); o.w = f2b(v.w);
        ((ushort4*)xb)[i] = o;
    }
    if (i < 256 * 128) {
        int k = i >> 7;
        int j = i & 127;
        float v = (k < 128) ? Ws[j * 128 + k] : Wn[j * 128 + (k - 128)];
        WT[i] = v;
    }
}

// ---------------- scan step 1: pad counts to even, per-block exclusive scan ----------------
__global__ __launch_bounds__(1024) void scan1_kernel(const int* __restrict__ count,
                                                     int* __restrict__ offsets,
                                                     int* __restrict__ bsum) {
    __shared__ int tmp[1024];
    int t = threadIdx.x;
    int gid = blockIdx.x * 1024 + t;
    int c = (count[gid] + 1) & ~1;        // pad each node to even edge count
    tmp[t] = c;
    __syncthreads();
    for (int off = 1; off < 1024; off <<= 1) {
        int v = (t >= off) ? tmp[t - off] : 0;
        __syncthreads();
        tmp[t] += v;
        __syncthreads();
    }
    offsets[gid] = tmp[t] - c;
    if (t == 1023) bsum[blockIdx.x] = tmp[t];
}

// ---------------- scan step 2+3: block-sum scan + add + cursor + explicit pad writes ----------------
__global__ __launch_bounds__(1024) void scan23_kernel(int* __restrict__ offsets,
                                                      const int* __restrict__ bsum,
                                                      int* __restrict__ cursor,
                                                      const int* __restrict__ count,
                                                      int2* __restrict__ edge_sw) {
    __shared__ int bs[64];
    int t = threadIdx.x;
    if (t < 64) {
        int orig = (t < NB_SCAN) ? bsum[t] : 0;
        int v = orig;
        #pragma unroll
        for (int off = 1; off < 64; off <<= 1) {
            int u = __shfl_up(v, off);
            if (t >= off) v += u;
        }
        bs[t] = v - orig;    // exclusive
    }
    __syncthreads();
    int gid = blockIdx.x * 1024 + t;
    int val = offsets[gid] + bs[blockIdx.x];
    offsets[gid] = val;
    cursor[gid] = val;
    int cnt = count[gid];
    if (cnt & 1) {
        // odd count -> one pad slot at the end of this node's segment; must read as {0, 0.0f}
        edge_sw[val + cnt] = make_int2(0, 0);
    }
}

// ---------------- permute edges into CSR order (plain L2-cached stores, 2 edges/thread) ----------------
__global__ __launch_bounds__(256) void csr_scatter_kernel(
        const int* __restrict__ src, const int* __restrict__ dst,
        const float* __restrict__ ew, int* __restrict__ cursor,
        int2* __restrict__ edge_sw, int E) {
    int e0 = (blockIdx.x * 256 + threadIdx.x) * 2;
    if (e0 >= E) return;
    int2   s2 = *(const int2*)(src + e0);
    int2   d2 = *(const int2*)(dst + e0);
    float2 w2 = *(const float2*)(ew + e0);
    int pos0 = atomicAdd(&cursor[d2.x], 1);
    edge_sw[pos0] = make_int2(s2.x, __float_as_int(w2.x));
    if (e0 + 1 < E) {
        int pos1 = atomicAdd(&cursor[d2.y], 1);
        edge_sw[pos1] = make_int2(s2.y, __float_as_int(w2.y));
    }
}

// ---------------- fused gather(bf16, 16-edge chunks) + dual GEMM + bias (R13 verbatim) ----------------
__global__ __launch_bounds__(256) void fused_out_kernel(
        const float* __restrict__ x, const ushort* __restrict__ xb,
        const int* __restrict__ offsets, const int2* __restrict__ edge_sw,
        const float* __restrict__ WT, const float* __restrict__ b_self,
        const float* __restrict__ bias, float* __restrict__ out) {
    __shared__ float HN[32][128];
    int tid = threadIdx.x;
    int v0 = blockIdx.x * 32;
    int lane = tid & 63;
    int wid = tid >> 6;
    int half = lane >> 5;
    int l32 = lane & 31;

    for (int q = 0; q < 8; ++q) {
        int nn = wid * 8 + q;
        int v = v0 + nn;
        float4 acc = make_float4(0.f, 0.f, 0.f, 0.f);
        float wsum = 0.f;
        if (v < NN) {
            int beg = offsets[v];
            int end = offsets[v + 1];
            int cnt = end - beg;               // even
            int i = beg;
            int n16 = cnt & ~15;
            for (; i < beg + n16; i += 16) {
                const int2* ebase = edge_sw + i + 8 * half;
                int4 mA = *(const int4*)(ebase + 0);
                int4 mB = *(const int4*)(ebase + 2);
                int4 mC = *(const int4*)(ebase + 4);
                int4 mD = *(const int4*)(ebase + 6);
                float w0 = __int_as_float(mA.y), w1 = __int_as_float(mA.w);
                float w2 = __int_as_float(mB.y), w3 = __int_as_float(mB.w);
                float w4 = __int_as_float(mC.y), w5 = __int_as_float(mC.w);
                float w6 = __int_as_float(mD.y), w7 = __int_as_float(mD.w);
                ushort4 r0 = *((const ushort4*)(xb + (size_t)mA.x * D) + l32);
                ushort4 r1 = *((const ushort4*)(xb + (size_t)mA.z * D) + l32);
                ushort4 r2 = *((const ushort4*)(xb + (size_t)mB.x * D) + l32);
                ushort4 r3 = *((const ushort4*)(xb + (size_t)mB.z * D) + l32);
                ushort4 r4 = *((const ushort4*)(xb + (size_t)mC.x * D) + l32);
                ushort4 r5 = *((const ushort4*)(xb + (size_t)mC.z * D) + l32);
                ushort4 r6 = *((const ushort4*)(xb + (size_t)mD.x * D) + l32);
                ushort4 r7 = *((const ushort4*)(xb + (size_t)mD.z * D) + l32);
                edge_fma4(acc, r0, w0); edge_fma4(acc, r1, w1);
                edge_fma4(acc, r2, w2); edge_fma4(acc, r3, w3);
                edge_fma4(acc, r4, w4); edge_fma4(acc, r5, w5);
                edge_fma4(acc, r6, w6); edge_fma4(acc, r7, w7);
                wsum += ((w0 + w1) + (w2 + w3)) + ((w4 + w5) + (w6 + w7));
            }
            if (cnt & 8) {
                const int2* ebase = edge_sw + i + 4 * half;
                int4 mA = *(const int4*)(ebase + 0);
                int4 mB = *(const int4*)(ebase + 2);
                float w0 = __int_as_float(mA.y), w1 = __int_as_float(mA.w);
                float w2 = __int_as_float(mB.y), w3 = __int_as_float(mB.w);
                ushort4 r0 = *((const ushort4*)(xb + (size_t)mA.x * D) + l32);
                ushort4 r1 = *((const ushort4*)(xb + (size_t)mA.z * D) + l32);
                ushort4 r2 = *((const ushort4*)(xb + (size_t)mB.x * D) + l32);
                ushort4 r3 = *((const ushort4*)(xb + (size_t)mB.z * D) + l32);
                edge_fma4(acc, r0, w0); edge_fma4(acc, r1, w1);
                edge_fma4(acc, r2, w2); edge_fma4(acc, r3, w3);
                wsum += (w0 + w1) + (w2 + w3);
                i += 8;
            }
            if (cnt & 4) {
                int4 mA = *(const int4*)(edge_sw + i + 2 * half);
                float w0 = __int_as_float(mA.y), w1 = __int_as_float(mA.w);
                ushort4 r0 = *((const ushort4*)(xb + (size_t)mA.x * D) + l32);
                ushort4 r1 = *((const ushort4*)(xb + (size_t)mA.z * D) + l32);
                edge_fma4(acc, r0, w0); edge_fma4(acc, r1, w1);
                wsum += w0 + w1;
                i += 4;
            }
            if ((cnt & 2) && half == 0) {
                int4 mA = *(const int4*)(edge_sw + i);
                float w0 = __int_as_float(mA.y), w1 = __int_as_float(mA.w);
                ushort4 r0 = *((const ushort4*)(xb + (size_t)mA.x * D) + l32);
                ushort4 r1 = *((const ushort4*)(xb + (size_t)mA.z * D) + l32);
                edge_fma4(acc, r0, w0); edge_fma4(acc, r1, w1);
                wsum += w0 + w1;
            }
        }
        acc.x += __shfl_xor(acc.x, 32);
        acc.y += __shfl_xor(acc.y, 32);
        acc.z += __shfl_xor(acc.z, 32);
        acc.w += __shfl_xor(acc.w, 32);
        wsum  += __shfl_xor(wsum, 32);
        if (half == 0) {
            float inv = 1.0f / (wsum + EPS);
            *(float4*)&HN[nn][l32 * 4] =
                make_float4(acc.x * inv, acc.y * inv, acc.z * inv, acc.w * inv);
        }
    }
    __syncthreads();

    int j0 = (tid & 31) * 4;
    int ns = tid >> 5;
    float acc[4][4];
    #pragma unroll
    for (int n = 0; n < 4; ++n)
        #pragma unroll
        for (int j = 0; j < 4; ++j) acc[n][j] = 0.f;

    int rowc[4];
    #pragma unroll
    for (int n = 0; n < 4; ++n) {
        int rv = v0 + ns * 4 + n;
        rowc[n] = (rv < NN) ? rv : (NN - 1);
    }

    for (int k4 = 0; k4 < 128; k4 += 4) {
        float4 w0 = *(const float4*)(WT + (k4 + 0) * D + j0);
        float4 w1 = *(const float4*)(WT + (k4 + 1) * D + j0);
        float4 w2 = *(const float4*)(WT + (k4 + 2) * D + j0);
        float4 w3 = *(const float4*)(WT + (k4 + 3) * D + j0);
        #pragma unroll
        for (int n = 0; n < 4; ++n) {
            float4 a = *(const float4*)(x + (size_t)rowc[n] * D + k4);
            acc[n][0] = fmaf(a.x, w0.x, fmaf(a.y, w1.x, fmaf(a.z, w2.x, fmaf(a.w, w3.x, acc[n][0]))));
            acc[n][1] = fmaf(a.x, w0.y, fmaf(a.y, w1.y, fmaf(a.z, w2.y, fmaf(a.w, w3.y, acc[n][1]))));
            acc[n][2] = fmaf(a.x, w0.z, fmaf(a.y, w1.z, fmaf(a.z, w2.z, fmaf(a.w, w3.z, acc[n][2]))));
            acc[n][3] = fmaf(a.x, w0.w, fmaf(a.y, w1.w, fmaf(a.z, w2.w, fmaf(a.w, w3.w, acc[n][3]))));
        }
    }
    for (int k4 = 0; k4 < 128; k4 += 4) {
        float4 w0 = *(const float4*)(WT + (128 + k4 + 0) * D + j0);
        float4 w1 = *(const float4*)(WT + (128 + k4 + 1) * D + j0);
        float4 w2 = *(const float4*)(WT + (128 + k4 + 2) * D + j0);
        float4 w3 = *(const float4*)(WT + (128 + k4 + 3) * D + j0);
        #pragma unroll
        for (int n = 0; n < 4; ++n) {
            float4 a = *(const float4*)&HN[ns * 4 + n][k4];
            acc[n][0] = fmaf(a.x, w0.x, fmaf(a.y, w1.x, fmaf(a.z, w2.x, fmaf(a.w, w3.x, acc[n][0]))));
            acc[n][1] = fmaf(a.x, w0.y, fmaf(a.y, w1.y, fmaf(a.z, w2.y, fmaf(a.w, w3.y, acc[n][1]))));
            acc[n][2] = fmaf(a.x, w0.z, fmaf(a.y, w1.z, fmaf(a.z, w2.z, fmaf(a.w, w3.z, acc[n][2]))));
            acc[n][3] = fmaf(a.x, w0.w, fmaf(a.y, w1.w, fmaf(a.z, w2.w, fmaf(a.w, w3.w, acc[n][3]))));
        }
    }

    float4 b  = *(const float4*)(b_self + j0);
    float4 bp = *(const float4*)(bias + j0);
    b.x += bp.x; b.y += bp.y; b.z += bp.z; b.w += bp.w;

    #pragma unroll
    for (int n = 0; n < 4; ++n) {
        int v = v0 + ns * 4 + n;
        if (v < NN) {
            float4 o;
            o.x = acc[n][0] + b.x;
            o.y = acc[n][1] + b.y;
            o.z = acc[n][2] + b.z;
            o.w = acc[n][3] + b.w;
            *(float4*)(out + (size_t)v * D + j0) = o;
        }
    }
}

extern "C" void kernel_launch(void* const* d_in, const int* in_sizes, int n_in,
                              void* d_out, int out_size, void* d_ws, size_t ws_size,
                              hipStream_t stream) {
    const float* x   = (const float*)d_in[0];
    const int*   src = (const int*)d_in[1];
    const int*   dst = (const int*)d_in[2];
    const float* ew  = (const float*)d_in[3];
    const float* Ws  = (const float*)d_in[4];
    const float* bs  = (const float*)d_in[5];
    const float* Wn  = (const float*)d_in[6];
    const float* bp  = (const float*)d_in[7];
    float* out = (float*)d_out;

    int E = in_sizes[1];
    int EPAD = E + NSCAN;                       // room for 1 pad edge per node

    // workspace layout (4B units)
    int*  wsi     = (int*)d_ws;
    int*  count   = wsi;                        // NSCAN
    int2* edge_sw = (int2*)(wsi + NSCAN);       // EPAD int2 (16B-aligned)
    int*  offsets = wsi + NSCAN + 2 * EPAD;     // NSCAN
    int*  cursor  = offsets + NSCAN;            // NSCAN
    int*  bsum    = cursor + NSCAN;             // 64
    float* WT     = (float*)(bsum + 64);        // 256*128 floats
    ushort* xb    = (ushort*)(WT + 256 * 128);  // NN*D bf16

    // zero only count (200 KB); pad slots written explicitly in scan23
    hipMemsetAsync(count, 0, (size_t)NSCAN * sizeof(int), stream);

    int ncvt = NN * D / 4;
    int nmax = (E > ncvt) ? E : ncvt;
    prep_kernel<<<(nmax + 255) / 256, 256, 0, stream>>>(dst, count, x, xb, Ws, Wn, WT, E);

    scan1_kernel<<<NB_SCAN, 1024, 0, stream>>>(count, offsets, bsum);
    scan23_kernel<<<NB_SCAN, 1024, 0, stream>>>(offsets, bsum, cursor, count, edge_sw);
    csr_scatter_kernel<<<(E / 2 + 255) / 256, 256, 0, stream>>>(src, dst, ew, cursor,
                                                                edge_sw, E);

    fused_out_kernel<<<(NN + 31) / 32, 256, 0, stream>>>(x, xb, offsets, edge_sw,
                                                         WT, bs, bp, out);
}

// Round 16
// 209.045 us; speedup vs baseline: 1.1111x; 1.0443x over previous
//
#include <hip/hip_runtime.h>

#define NN 50000
#define D 128
#define EPS 1e-8f
#define NSCAN 50176          // 49 * 1024 >= NN
#define NB_SCAN 49
#define CVT_BLOCKS 512

__device__ __forceinline__ unsigned short f2b(float f) {
    unsigned int u = __float_as_uint(f);
    u += 0x7FFFu + ((u >> 16) & 1u);      // round-to-nearest-even
    return (unsigned short)(u >> 16);
}
__device__ __forceinline__ float b2f(unsigned short s) {
    return __uint_as_float(((unsigned int)s) << 16);
}

__device__ __forceinline__ void edge_fma4(float4& a, ushort4 r, float w) {
    a.x = fmaf(b2f(r.x), w, a.x);
    a.y = fmaf(b2f(r.y), w, a.y);
    a.z = fmaf(b2f(r.z), w, a.z);
    a.w = fmaf(b2f(r.w), w, a.w);
}

// ---------------- histogram of dst ----------------
__global__ __launch_bounds__(256) void hist_kernel(const int* __restrict__ dst,
                                                   int* __restrict__ count, int E) {
    int e = blockIdx.x * 256 + threadIdx.x;
    if (e < E) atomicAdd(&count[dst[e]], 1);
}

// ---------------- scan step 1 (blocks <49) + x->bf16 convert (blocks >=49) ----------------
__global__ __launch_bounds__(1024) void scan1_cvt_kernel(
        const int* __restrict__ count, int* __restrict__ offsets, int* __restrict__ bsum,
        const float* __restrict__ x, ushort* __restrict__ xb) {
    int b = blockIdx.x;
    if (b >= NB_SCAN) {
        const int n4 = NN * D / 4;
        for (int i = (b - NB_SCAN) * 1024 + threadIdx.x; i < n4; i += CVT_BLOCKS * 1024) {
            float4 v = ((const float4*)x)[i];
            ushort4 o;
            o.x = f2b(v.x); o.y = f2b(v.y); o.z = f2b(v.z); o.w = f2b(v.w);
            ((ushort4*)xb)[i] = o;
        }
        return;
    }
    __shared__ int tmp[1024];
    int t = threadIdx.x;
    int gid = b * 1024 + t;
    int c = (count[gid] + 1) & ~1;        // pad each node to even edge count
    tmp[t] = c;
    __syncthreads();
    for (int off = 1; off < 1024; off <<= 1) {
        int v = (t >= off) ? tmp[t - off] : 0;
        __syncthreads();
        tmp[t] += v;
        __syncthreads();
    }
    offsets[gid] = tmp[t] - c;
    if (t == 1023) bsum[b] = tmp[t];
}

// ---------------- scan 2+3 + pad writes (blocks <49) + WT build (blocks >=49) ----------------
__global__ __launch_bounds__(1024) void scan23_wt_kernel(
        int* __restrict__ offsets, const int* __restrict__ bsum, int* __restrict__ cursor,
        const int* __restrict__ count, int2* __restrict__ edge_sw,
        const float* __restrict__ Ws, const float* __restrict__ Wn, float* __restrict__ WT) {
    int b = blockIdx.x;
    int t = threadIdx.x;
    if (b >= NB_SCAN) {
        int i = (b - NB_SCAN) * 1024 + t;   // 32 blocks * 1024 = 32768 exactly
        int k = i >> 7;
        int j = i & 127;
        float v = (k < 128) ? Ws[j * 128 + k] : Wn[j * 128 + (k - 128)];
        WT[i] = v;
        return;
    }
    __shared__ int bs[64];
    if (t < 64) {
        int orig = (t < NB_SCAN) ? bsum[t] : 0;
        int v = orig;
        #pragma unroll
        for (int off = 1; off < 64; off <<= 1) {
            int u = __shfl_up(v, off);
            if (t >= off) v += u;
        }
        bs[t] = v - orig;    // exclusive
    }
    __syncthreads();
    int gid = b * 1024 + t;
    int val = offsets[gid] + bs[b];
    offsets[gid] = val;
    cursor[gid] = val;
    int cnt = count[gid];
    if (cnt & 1) {
        // odd count -> one pad slot at segment end; must read as {src=0, w=0.0f}
        edge_sw[val + cnt] = make_int2(0, 0);
    }
}

// ---------------- permute edges into CSR order (plain L2-cached stores) ----------------
__global__ __launch_bounds__(256) void csr_scatter_kernel(
        const int* __restrict__ src, const int* __restrict__ dst,
        const float* __restrict__ ew, int* __restrict__ cursor,
        int2* __restrict__ edge_sw, int E) {
    int e = blockIdx.x * 256 + threadIdx.x;
    if (e >= E) return;
    int d = dst[e];
    int pos = atomicAdd(&cursor[d], 1);
    edge_sw[pos] = make_int2(src[e], __float_as_int(ew[e]));
}

// ---------------- fused gather(bf16, 8-edge chunks) + dual GEMM + bias (R9 verbatim) ----------------
__global__ __launch_bounds__(256) void fused_out_kernel(
        const float* __restrict__ x, const ushort* __restrict__ xb,
        const int* __restrict__ offsets, const int2* __restrict__ edge_sw,
        const float* __restrict__ WT, const float* __restrict__ b_self,
        const float* __restrict__ bias, float* __restrict__ out) {
    __shared__ float HN[32][128];
    int tid = threadIdx.x;
    int v0 = blockIdx.x * 32;
    int lane = tid & 63;
    int wid = tid >> 6;
    int half = lane >> 5;
    int l32 = lane & 31;

    for (int q = 0; q < 8; ++q) {
        int nn = wid * 8 + q;
        int v = v0 + nn;
        float4 acc = make_float4(0.f, 0.f, 0.f, 0.f);
        float wsum = 0.f;
        if (v < NN) {
            int beg = offsets[v];
            int end = offsets[v + 1];
            int cnt = end - beg;               // even
            int i = beg;
            int n8 = cnt & ~7;
            for (; i < beg + n8; i += 8) {
                int4 mA = *(const int4*)(edge_sw + i + 4 * half);
                int4 mB = *(const int4*)(edge_sw + i + 4 * half + 2);
                float w0 = __int_as_float(mA.y), w1 = __int_as_float(mA.w);
                float w2 = __int_as_float(mB.y), w3 = __int_as_float(mB.w);
                ushort4 r0 = *((const ushort4*)(xb + (size_t)mA.x * D) + l32);
                ushort4 r1 = *((const ushort4*)(xb + (size_t)mA.z * D) + l32);
                ushort4 r2 = *((const ushort4*)(xb + (size_t)mB.x * D) + l32);
                ushort4 r3 = *((const ushort4*)(xb + (size_t)mB.z * D) + l32);
                edge_fma4(acc, r0, w0); edge_fma4(acc, r1, w1);
                edge_fma4(acc, r2, w2); edge_fma4(acc, r3, w3);
                wsum += (w0 + w1) + (w2 + w3);
            }
            if (cnt & 4) {
                int4 mA = *(const int4*)(edge_sw + i + 2 * half);
                float w0 = __int_as_float(mA.y), w1 = __int_as_float(mA.w);
                ushort4 r0 = *((const ushort4*)(xb + (size_t)mA.x * D) + l32);
                ushort4 r1 = *((const ushort4*)(xb + (size_t)mA.z * D) + l32);
                edge_fma4(acc, r0, w0); edge_fma4(acc, r1, w1);
                wsum += w0 + w1;
                i += 4;
            }
            if ((cnt & 2) && half == 0) {
                int4 mA = *(const int4*)(edge_sw + i);
                float w0 = __int_as_float(mA.y), w1 = __int_as_float(mA.w);
                ushort4 r0 = *((const ushort4*)(xb + (size_t)mA.x * D) + l32);
                ushort4 r1 = *((const ushort4*)(xb + (size_t)mA.z * D) + l32);
                edge_fma4(acc, r0, w0); edge_fma4(acc, r1, w1);
                wsum += w0 + w1;
            }
        }
        acc.x += __shfl_xor(acc.x, 32);
        acc.y += __shfl_xor(acc.y, 32);
        acc.z += __shfl_xor(acc.z, 32);
        acc.w += __shfl_xor(acc.w, 32);
        wsum  += __shfl_xor(wsum, 32);
        if (half == 0) {
            float inv = 1.0f / (wsum + EPS);
            *(float4*)&HN[nn][l32 * 4] =
                make_float4(acc.x * inv, acc.y * inv, acc.z * inv, acc.w * inv);
        }
    }
    __syncthreads();

    int j0 = (tid & 31) * 4;
    int ns = tid >> 5;
    float acc[4][4];
    #pragma unroll
    for (int n = 0; n < 4; ++n)
        #pragma unroll
        for (int j = 0; j < 4; ++j) acc[n][j] = 0.f;

    int rowc[4];
    #pragma unroll
    for (int n = 0; n < 4; ++n) {
        int rv = v0 + ns * 4 + n;
        rowc[n] = (rv < NN) ? rv : (NN - 1);
    }

    for (int k4 = 0; k4 < 128; k4 += 4) {
        float4 w0 = *(const float4*)(WT + (k4 + 0) * D + j0);
        float4 w1 = *(const float4*)(WT + (k4 + 1) * D + j0);
        float4 w2 = *(const float4*)(WT + (k4 + 2) * D + j0);
        float4 w3 = *(const float4*)(WT + (k4 + 3) * D + j0);
        #pragma unroll
        for (int n = 0; n < 4; ++n) {
            float4 a = *(const float4*)(x + (size_t)rowc[n] * D + k4);
            acc[n][0] = fmaf(a.x, w0.x, fmaf(a.y, w1.x, fmaf(a.z, w2.x, fmaf(a.w, w3.x, acc[n][0]))));
            acc[n][1] = fmaf(a.x, w0.y, fmaf(a.y, w1.y, fmaf(a.z, w2.y, fmaf(a.w, w3.y, acc[n][1]))));
            acc[n][2] = fmaf(a.x, w0.z, fmaf(a.y, w1.z, fmaf(a.z, w2.z, fmaf(a.w, w3.z, acc[n][2]))));
            acc[n][3] = fmaf(a.x, w0.w, fmaf(a.y, w1.w, fmaf(a.z, w2.w, fmaf(a.w, w3.w, acc[n][3]))));
        }
    }
    for (int k4 = 0; k4 < 128; k4 += 4) {
        float4 w0 = *(const float4*)(WT + (128 + k4 + 0) * D + j0);
        float4 w1 = *(const float4*)(WT + (128 + k4 + 1) * D + j0);
        float4 w2 = *(const float4*)(WT + (128 + k4 + 2) * D + j0);
        float4 w3 = *(const float4*)(WT + (128 + k4 + 3) * D + j0);
        #pragma unroll
        for (int n = 0; n < 4; ++n) {
            float4 a = *(const float4*)&HN[ns * 4 + n][k4];
            acc[n][0] = fmaf(a.x, w0.x, fmaf(a.y, w1.x, fmaf(a.z, w2.x, fmaf(a.w, w3.x, acc[n][0]))));
            acc[n][1] = fmaf(a.x, w0.y, fmaf(a.y, w1.y, fmaf(a.z, w2.y, fmaf(a.w, w3.y, acc[n][1]))));
            acc[n][2] = fmaf(a.x, w0.z, fmaf(a.y, w1.z, fmaf(a.z, w2.z, fmaf(a.w, w3.z, acc[n][2]))));
            acc[n][3] = fmaf(a.x, w0.w, fmaf(a.y, w1.w, fmaf(a.z, w2.w, fmaf(a.w, w3.w, acc[n][3]))));
        }
    }

    float4 b  = *(const float4*)(b_self + j0);
    float4 bp = *(const float4*)(bias + j0);
    b.x += bp.x; b.y += bp.y; b.z += bp.z; b.w += bp.w;

    #pragma unroll
    for (int n = 0; n < 4; ++n) {
        int v = v0 + ns * 4 + n;
        if (v < NN) {
            float4 o;
            o.x = acc[n][0] + b.x;
            o.y = acc[n][1] + b.y;
            o.z = acc[n][2] + b.z;
            o.w = acc[n][3] + b.w;
            *(float4*)(out + (size_t)v * D + j0) = o;
        }
    }
}

extern "C" void kernel_launch(void* const* d_in, const int* in_sizes, int n_in,
                              void* d_out, int out_size, void* d_ws, size_t ws_size,
                              hipStream_t stream) {
    const float* x   = (const float*)d_in[0];
    const int*   src = (const int*)d_in[1];
    const int*   dst = (const int*)d_in[2];
    const float* ew  = (const float*)d_in[3];
    const float* Ws  = (const float*)d_in[4];
    const float* bs  = (const float*)d_in[5];
    const float* Wn  = (const float*)d_in[6];
    const float* bp  = (const float*)d_in[7];
    float* out = (float*)d_out;

    int E = in_sizes[1];
    int EPAD = E + NSCAN;                       // room for 1 pad edge per node

    // workspace layout (4B units)
    int*  wsi     = (int*)d_ws;
    int*  count   = wsi;                        // NSCAN
    int2* edge_sw = (int2*)(wsi + NSCAN);       // EPAD int2 (16B-aligned)
    int*  offsets = wsi + NSCAN + 2 * EPAD;     // NSCAN
    int*  cursor  = offsets + NSCAN;            // NSCAN
    int*  bsum    = cursor + NSCAN;             // 64
    float* WT     = (float*)(bsum + 64);        // 256*128 floats
    ushort* xb    = (ushort*)(WT + 256 * 128);  // NN*D bf16

    // zero only count (200 KB); pad slots written explicitly in scan23
    hipMemsetAsync(count, 0, (size_t)NSCAN * sizeof(int), stream);

    hist_kernel<<<(E + 255) / 256, 256, 0, stream>>>(dst, count, E);
    scan1_cvt_kernel<<<NB_SCAN + CVT_BLOCKS, 1024, 0, stream>>>(count, offsets, bsum, x, xb);
    scan23_wt_kernel<<<NB_SCAN + 32, 1024, 0, stream>>>(offsets, bsum, cursor, count,
                                                        edge_sw, Ws, Wn, WT);
    csr_scatter_kernel<<<(E + 255) / 256, 256, 0, stream>>>(src, dst, ew, cursor, edge_sw, E);

    fused_out_kernel<<<(NN + 31) / 32, 256, 0, stream>>>(x, xb, offsets, edge_sw,
                                                         WT, bs, bp, out);
}